// Round 5
// baseline (672.797 us; speedup 1.0000x reference)
//
#include <hip/hip_runtime.h>

// Problem constants (fixed by setup_inputs: H=W=256, WIN=8, NCAV=2, C=256, HEADS=8)
#define NT   64
#define CDIM 256
#define NHEAD 8
#define SCALE 0.17677669529663687f   // hd^-0.5 = 1/sqrt(32)
#define PI_F 3.14159265358979f

typedef short bfrag __attribute__((ext_vector_type(8)));   // 8 bf16 (4 VGPRs)
typedef float f4    __attribute__((ext_vector_type(4)));   // MFMA C/D
typedef unsigned short us4 __attribute__((ext_vector_type(4)));

__device__ __forceinline__ unsigned short f2bf(float f){
  unsigned u = __builtin_bit_cast(unsigned, f);
  u += 0x7FFFu + ((u >> 16) & 1u);       // round-to-nearest-even
  return (unsigned short)(u >> 16);
}
__device__ __forceinline__ unsigned pk2(float a, float b){
  return (unsigned)f2bf(a) | ((unsigned)f2bf(b) << 16);
}
__device__ __forceinline__ f4 mfma16(bfrag a, bfrag b, f4 c){
  return __builtin_amdgcn_mfma_f32_16x16x32_bf16(a, b, c, 0, 0, 0);
}
// swizzle: 64 rows x 32 16B-units/row; unit ^= row&7 -> 2-way (free)
__device__ __forceinline__ int swx(int row, int u){ return (row << 5) + (u ^ (row & 7)); }

// Convert MFMA C-layout (2 mt-tiles of one 16-token tile: lane holds tok=cc,
// d = mt*16+quad*4+r) to MFMA input-frag layout (lane holds tok=cc, d=quad*8+e).
__device__ __forceinline__ bfrag xpose(f4 m0, f4 m1, int quad, int cc){
  int P0m0 = (int)pk2(m0[0], m0[1]);
  int P1m0 = (int)pk2(m0[2], m0[3]);
  int P0m1 = (int)pk2(m1[0], m1[1]);
  int P1m1 = (int)pk2(m1[2], m1[3]);
  int srcA = ((quad & 1) << 5) + cc;
  int srcB = srcA + 16;
  int hi = quad >> 1;
  int a0 = __shfl(P0m0, srcA, 64), a1 = __shfl(P0m1, srcA, 64);
  int b0 = __shfl(P1m0, srcA, 64), b1 = __shfl(P1m1, srcA, 64);
  int c0 = __shfl(P0m0, srcB, 64), c1 = __shfl(P0m1, srcB, 64);
  int d0 = __shfl(P1m0, srcB, 64), d1 = __shfl(P1m1, srcB, 64);
  union { bfrag f; int u[4]; } r;
  r.u[0] = hi ? a1 : a0;
  r.u[1] = hi ? b1 : b0;
  r.u[2] = hi ? c1 : c0;
  r.u[3] = hi ? d1 : d0;
  return r.f;
}

// 32ch x 32tok sub-GEMM: A = wt rows [ocb,ocb+32), B = x tokens [tb,tb+32) from LDS.
__device__ __forceinline__ void subgemm32(const unsigned short* __restrict__ wt,
                                          const unsigned short* lx,
                                          const float* __restrict__ bqkv,
                                          int ocb, int tb, int quad, int cc,
                                          bfrag& f0, bfrag& f1)
{
  f4 acc[2][2];
  acc[0][0] = (f4){0,0,0,0}; acc[0][1] = (f4){0,0,0,0};
  acc[1][0] = (f4){0,0,0,0}; acc[1][1] = (f4){0,0,0,0};
  #pragma unroll
  for (int ks = 0; ks < 8; ++ks){
    bfrag a0 = *(const bfrag*)(wt + (ocb +      cc)*256 + ks*32 + quad*8);
    bfrag a1 = *(const bfrag*)(wt + (ocb + 16 + cc)*256 + ks*32 + quad*8);
    bfrag b0 = *(const bfrag*)(&lx[swx(tb +      cc, ks*4 + quad)*8]);
    bfrag b1 = *(const bfrag*)(&lx[swx(tb + 16 + cc, ks*4 + quad)*8]);
    acc[0][0] = mfma16(a0, b0, acc[0][0]);
    acc[0][1] = mfma16(a0, b1, acc[0][1]);
    acc[1][0] = mfma16(a1, b0, acc[1][0]);
    acc[1][1] = mfma16(a1, b1, acc[1][1]);
  }
  #pragma unroll
  for (int mt = 0; mt < 2; ++mt)
    #pragma unroll
    for (int r = 0; r < 4; ++r){
      float bb = bqkv[ocb + mt*16 + quad*4 + r];
      acc[mt][0][r] += bb;
      acc[mt][1][r] += bb;
    }
  f0 = xpose(acc[0][0], acc[1][0], quad, cc);
  f1 = xpose(acc[0][1], acc[1][1], quad, cc);
}

// S (QK^T) for one 16-row tile, biases added IN PLACE into the accumulator,
// row stats Z = m + log(sum). SA[jt][r] = logits, Z[r] = log-normalizer.
__device__ __forceinline__ void logits_it(bfrag aq, int iibase, int quad, int cc, int h,
    const unsigned short* kfr, const float* __restrict__ relt, float ego,
    f4 (&SA)[4], float (&Z)[4])
{
  #pragma unroll
  for (int jt = 0; jt < 4; ++jt){
    bfrag bk = *(const bfrag*)(kfr + jt*512 + (quad*16 + cc)*8);
    f4 z = (f4){0,0,0,0};
    SA[jt] = mfma16(aq, bk, z);
  }
  #pragma unroll
  for (int jt = 0; jt < 4; ++jt){
    int jj = jt*16 + cc;
    int yj = jj >> 3, xj = jj & 7;
    #pragma unroll
    for (int r = 0; r < 4; ++r){
      int ii = iibase + r;
      int ridx = ((ii >> 3) - yj + 7)*15 + ((ii & 7) - xj + 7);
      SA[jt][r] += relt[ridx*8 + h] + ego;
    }
  }
  #pragma unroll
  for (int r = 0; r < 4; ++r){
    float m = fmaxf(fmaxf(SA[0][r], SA[1][r]), fmaxf(SA[2][r], SA[3][r]));
    for (int off = 1; off < 16; off <<= 1) m = fmaxf(m, __shfl_xor(m, off, 64));
    float s = 0.0f;
    #pragma unroll
    for (int jt = 0; jt < 4; ++jt) s += __expf(SA[jt][r] - m);
    for (int off = 1; off < 16; off <<= 1) s += __shfl_xor(s, off, 64);
    Z[r] = m + __logf(s);
  }
}

// Blended P (16 rows x 32 j per chunk) -> wave-private LDS tile -> PV MFMA.
__device__ __forceinline__ void pv_it(const f4 (&SA)[4], const float (&Z)[4],
    int quad, int cc, unsigned short* Pt, const unsigned short* vts,
    float ws0, float ws1, f4* yit)
{
  #pragma unroll
  for (int chunk = 0; chunk < 2; ++chunk){
    #pragma unroll
    for (int jtl = 0; jtl < 2; ++jtl){
      int jt = chunk*2 + jtl;
      #pragma unroll
      for (int r = 0; r < 4; ++r){
        float av = SA[jt][r];
        float rl = fmaxf(av, 0.0f);
        float p = ws0 * __expf(av - Z[r]) + ws1 * rl * rl;
        Pt[(quad*4 + r)*32 + jtl*16 + cc] = f2bf(p);
      }
    }
    bfrag pa = *(const bfrag*)(&Pt[cc*32 + quad*8]);
    #pragma unroll
    for (int nt = 0; nt < 2; ++nt){
      int row = nt*16 + cc;
      bfrag pb = *(const bfrag*)(&vts[row*64 + (((chunk*4 + quad) ^ (row & 7)) << 3)]);
      yit[nt] = mfma16(pa, pb, yit[nt]);
    }
  }
}

// ---------------------------------------------------------------------------
// Prep: bf16 W^T (q-scaled) + fused qkv bias. (rel/ego tables now computed
// in-kernel: relt is 7 KiB L1-resident; ego dmax has a 4-corner closed form.)
// ---------------------------------------------------------------------------
__global__ void prep_kernel(const float* __restrict__ Wq,  const float* __restrict__ bq,
                            const float* __restrict__ Wkv, const float* __restrict__ bkv,
                            const float* __restrict__ Wp,
                            unsigned short* __restrict__ wt, float* __restrict__ bqkv)
{
  const int bid = blockIdx.x, tid = threadIdx.x;
  if (bid < 256) {                        // tiled weight transpose + bf16
    __shared__ float t[32][33];
    const int r0 = (bid >> 3) * 32;
    const int c0 = (bid & 7) * 32;
    const int rl = tid & 31, ch = tid >> 5;
    for (int k = 0; k < 4; ++k){
      int c = c0 + ch + k*8, r = r0 + rl;
      float v;
      if (r < 256)      v = Wq[c*256 + r] * SCALE;
      else if (r < 768) v = Wkv[c*512 + (r - 256)];
      else              v = Wp[c*256 + (r - 768)];
      t[rl][ch + k*8] = v;
    }
    __syncthreads();
    for (int k = 0; k < 4; ++k){
      int orr = ch + k*8;
      wt[(r0 + orr)*256 + c0 + rl] = f2bf(t[orr][rl]);
    }
  } else {                                // fused qkv bias (q part scaled)
    for (int j = tid; j < 768; j += 256)
      bqkv[j] = (j < 256) ? bq[j]*SCALE : bkv[j - 256];
  }
}

// ---------------------------------------------------------------------------
// Fused window attention: one block per window, 1024 threads (16 waves).
// LDS = 80 KiB -> exactly 2 blocks/CU (8 waves/SIMD):
//   ldsA 32K: x bf16 swizzled -> vT per head (32x64 swizzled)
//   ldsB 32K: k frags (lane-indexed) -> y bf16 swizzled
//   ldsP 16K: wave-private P tiles (16 rows x 32 j)
// it-sequential phase 2 keeps peak live regs ~56 (fits the 64-VGPR cap).
// ---------------------------------------------------------------------------
__global__ __launch_bounds__(1024, 8) void attn_kernel(
    const float* __restrict__ x, const float* __restrict__ wvec,
    const float* __restrict__ bp, float* __restrict__ out,
    const unsigned short* __restrict__ wt, const float* __restrict__ bqkv,
    const float* __restrict__ relt, const float* __restrict__ egot,
    const float* __restrict__ aff)
{
  __shared__ unsigned short ldsA[NT*CDIM];       // 32 KiB
  __shared__ unsigned short ldsB[NT*CDIM];       // 32 KiB
  __shared__ unsigned short ldsP[8192];          // 16 KiB

  const int b = blockIdx.x;
  const int tid = threadIdx.x;
  const int wv = tid >> 6, lane = tid & 63;
  const int quad = lane >> 4, cc = lane & 15;
  const int h = wv >> 1, half = wv & 1;

  // ---- stage x window -> bf16 ldsA (swizzled) ----
  const float4* xg = (const float4*)(x + (size_t)b*(NT*CDIM));
  for (int it = 0; it < 4; ++it){
    int i4 = tid + it*1024;
    float4 v = xg[i4];
    us4 pk = { f2bf(v.x), f2bf(v.y), f2bf(v.z), f2bf(v.w) };
    int row = i4 >> 6, u = (i4 & 63) >> 1, hf = i4 & 1;
    *(us4*)(&ldsA[swx(row, u)*8 + hf*4]) = pk;
  }
  // softmax-weights blend + ego bias (closed-form dmax over 4 grid corners)
  float w0 = wvec[0], w1 = wvec[1];
  float wm = fmaxf(w0, w1);
  float e0 = __expf(w0 - wm), e1 = __expf(w1 - wm);
  float ws0 = e0/(e0+e1), ws1 = e1/(e0+e1);
  float ego;
  {
    float ex0=(aff[0]+aff[1])*128.f+aff[2],  ey0=(aff[3]+aff[4])*128.f+aff[5];
    float ex1=(aff[6]+aff[7])*128.f+aff[8],  ey1=(aff[9]+aff[10])*128.f+aff[11];
    float dmax = 0.f;
    #pragma unroll
    for (int c = 0; c < 4; ++c){
      float cx = (c & 1) ? 252.f : 4.f, cy = (c >> 1) ? 252.f : 4.f;
      float d0x=cx-ex0, d0y=cy-ey0, d1x=cx-ex1, d1y=cy-ey1;
      dmax = fmaxf(dmax, fmaxf(sqrtf(d0x*d0x+d0y*d0y), sqrtf(d1x*d1x+d1y*d1y)));
    }
    dmax += 1e-6f;
    int cv = b >> 10, wi = b & 1023;
    float cx = (float)((wi & 31)*8 + 4), cy = (float)((wi >> 5)*8 + 4);
    float ex = cv ? ex1 : ex0, ey = cv ? ey1 : ey0;
    float dx = cx - ex, dy = cy - ey;
    float dd = sqrtf(dx*dx + dy*dy);
    float ang = atan2f(dy, dx);
    int db = (int)(dd/dmax*3.0f);
    int ab = (int)((ang + PI_F)/(2.0f*PI_F)*3.0f);
    ego = egot[(db*4 + ab)*8 + h];
  }
  __syncthreads();                               // b0: x staged

  // ---- phase 1: per-wave (head h, token-half) q,k,v ----
  bfrag aq0, aq1;
  subgemm32(wt, ldsA, bqkv, h*32, half*32, quad, cc, aq0, aq1);          // q -> regs
  {
    bfrag kf0, kf1;                                                       // k -> ldsB
    subgemm32(wt, ldsA, bqkv, 256 + h*32, half*32, quad, cc, kf0, kf1);
    *(bfrag*)(&ldsB[h*2048 + (half*2 + 0)*512 + lane*8]) = kf0;
    *(bfrag*)(&ldsB[h*2048 + (half*2 + 1)*512 + lane*8]) = kf1;
  }
  f4 vacc[2][2];                                                          // v -> regs (C-layout)
  {
    vacc[0][0] = (f4){0,0,0,0}; vacc[0][1] = (f4){0,0,0,0};
    vacc[1][0] = (f4){0,0,0,0}; vacc[1][1] = (f4){0,0,0,0};
    const int ocb = 512 + h*32, tb = half*32;
    #pragma unroll
    for (int ks = 0; ks < 8; ++ks){
      bfrag a0 = *(const bfrag*)(wt + (ocb +      cc)*256 + ks*32 + quad*8);
      bfrag a1 = *(const bfrag*)(wt + (ocb + 16 + cc)*256 + ks*32 + quad*8);
      bfrag b0 = *(const bfrag*)(&ldsA[swx(tb +      cc, ks*4 + quad)*8]);
      bfrag b1 = *(const bfrag*)(&ldsA[swx(tb + 16 + cc, ks*4 + quad)*8]);
      vacc[0][0] = mfma16(a0, b0, vacc[0][0]);
      vacc[0][1] = mfma16(a0, b1, vacc[0][1]);
      vacc[1][0] = mfma16(a1, b0, vacc[1][0]);
      vacc[1][1] = mfma16(a1, b1, vacc[1][1]);
    }
  }
  __syncthreads();                               // b1: x reads + k writes done

  // ---- vT (bias-added) into former x region (ldsA), swizzled [d][tok] ----
  {
    unsigned short* vs = &ldsA[h*2048];
    #pragma unroll
    for (int mt = 0; mt < 2; ++mt)
      #pragma unroll
      for (int ntl = 0; ntl < 2; ++ntl){
        int tok = half*32 + ntl*16 + cc;
        int tu = tok >> 3, te = tok & 7;
        #pragma unroll
        for (int r = 0; r < 4; ++r){
          int d = mt*16 + quad*4 + r;
          vs[d*64 + ((tu ^ (d & 7)) << 3) + te] =
              f2bf(vacc[mt][ntl][r] + bqkv[512 + h*32 + d]);
        }
      }
  }

  // ---- phase 2 (it-sequential): S0 -> b2 -> PV0 -> S1 -> PV1 ----
  f4 SA[4]; float Z[4];
  f4 yacc[2][2];
  yacc[0][0] = (f4){0,0,0,0}; yacc[0][1] = (f4){0,0,0,0};
  yacc[1][0] = (f4){0,0,0,0}; yacc[1][1] = (f4){0,0,0,0};
  unsigned short* Pt = &ldsP[wv*512];
  const unsigned short* kfr = &ldsB[h*2048];
  const unsigned short* vts = &ldsA[h*2048];

  logits_it(aq0, half*32 + 0*16 + quad*4, quad, cc, h, kfr, relt, ego, SA, Z);
  __syncthreads();                               // b2: vT writes visible
  pv_it(SA, Z, quad, cc, Pt, vts, ws0, ws1, yacc[0]);
  logits_it(aq1, half*32 + 1*16 + quad*4, quad, cc, h, kfr, relt, ego, SA, Z);
  pv_it(SA, Z, quad, cc, Pt, vts, ws0, ws1, yacc[1]);
  __syncthreads();                               // b3: all k reads + PV done

  // y (64x256 bf16, token-major, swizzled) into ldsB
  #pragma unroll
  for (int itl = 0; itl < 2; ++itl)
    #pragma unroll
    for (int nt = 0; nt < 2; ++nt)
      #pragma unroll
      for (int r = 0; r < 4; ++r){
        int ii = half*32 + itl*16 + quad*4 + r;
        int col = h*32 + nt*16 + cc;
        ldsB[swx(ii, col>>3)*8 + (col&7)] = f2bf(yacc[itl][nt][r]);
      }
  __syncthreads();                               // b4: y staged

  // ---- phase 3: out = y @ Wp + bp ----
  {
    const int mt = wv & 3;
    const int cb = (wv >> 2)*64;
    f4 o[4];
    #pragma unroll
    for (int nt = 0; nt < 4; ++nt) o[nt] = (f4){0,0,0,0};
    #pragma unroll
    for (int ks = 0; ks < 8; ++ks){
      bfrag ay = *(const bfrag*)(&ldsB[swx(mt*16 + cc, ks*4 + quad)*8]);
      #pragma unroll
      for (int nt = 0; nt < 4; ++nt){
        bfrag bw = *(const bfrag*)(wt + (768 + cb + nt*16 + cc)*256 + ks*32 + quad*8);
        o[nt] = mfma16(ay, bw, o[nt]);
      }
    }
    float* og = out + (size_t)b*(NT*CDIM);
    #pragma unroll
    for (int nt = 0; nt < 4; ++nt){
      int col = cb + nt*16 + cc;
      float bpv = bp[col];
      #pragma unroll
      for (int r = 0; r < 4; ++r){
        int tok = mt*16 + quad*4 + r;
        og[tok*256 + col] = o[nt][r] + bpv;
      }
    }
  }
}

extern "C" void kernel_launch(void* const* d_in, const int* in_sizes, int n_in,
                              void* d_out, int out_size, void* d_ws, size_t ws_size,
                              hipStream_t stream)
{
  const float* x    = (const float*)d_in[0];
  const float* aff  = (const float*)d_in[1];
  const float* Wq   = (const float*)d_in[2];
  const float* bq   = (const float*)d_in[3];
  const float* Wkv  = (const float*)d_in[4];
  const float* bkv  = (const float*)d_in[5];
  const float* Wp   = (const float*)d_in[6];
  const float* bp   = (const float*)d_in[7];
  const float* relt = (const float*)d_in[8];
  const float* egot = (const float*)d_in[9];
  const float* w    = (const float*)d_in[10];
  float* out = (float*)d_out;

  char* ws = (char*)d_ws;
  unsigned short* wt = (unsigned short*)ws;       // 512 KiB bf16 W^T
  float* bqkv = (float*)(ws + 524288);            //   3 KiB

  hipLaunchKernelGGL(prep_kernel, dim3(257), dim3(256), 0, stream,
                     Wq, bq, Wkv, bkv, Wp, wt, bqkv);
  hipLaunchKernelGGL(attn_kernel, dim3(2048), dim3(1024), 0, stream,
                     x, w, bp, out, wt, bqkv, relt, egot, aff);
}

// Round 6
// 570.517 us; speedup vs baseline: 1.1793x; 1.1793x over previous
//
#include <hip/hip_runtime.h>

// Problem constants (fixed by setup_inputs: H=W=256, WIN=8, NCAV=2, C=256, HEADS=8)
#define NT   64
#define CDIM 256
#define NHEAD 8
#define SCALE 0.17677669529663687f   // hd^-0.5 = 1/sqrt(32)
#define PI_F 3.14159265358979f

typedef short bfrag __attribute__((ext_vector_type(8)));   // 8 bf16 (4 VGPRs)
typedef float f4    __attribute__((ext_vector_type(4)));   // MFMA C/D
typedef unsigned short us4 __attribute__((ext_vector_type(4)));

__device__ __forceinline__ unsigned short f2bf(float f){
  unsigned u = __builtin_bit_cast(unsigned, f);
  u += 0x7FFFu + ((u >> 16) & 1u);       // round-to-nearest-even
  return (unsigned short)(u >> 16);
}
__device__ __forceinline__ unsigned pk2(float a, float b){
  return (unsigned)f2bf(a) | ((unsigned)f2bf(b) << 16);
}
__device__ __forceinline__ f4 mfma16(bfrag a, bfrag b, f4 c){
  return __builtin_amdgcn_mfma_f32_16x16x32_bf16(a, b, c, 0, 0, 0);
}
// swizzle: 64 rows x 32 16B-units/row; unit ^= row&7 -> 2-way (free)
__device__ __forceinline__ int swx(int row, int u){ return (row << 5) + (u ^ (row & 7)); }

// Convert MFMA C-layout (2 mt-tiles of one 16-token tile: lane holds tok=cc,
// d = mt*16+quad*4+r) to MFMA input-frag layout (lane holds tok=cc, d=quad*8+e).
__device__ __forceinline__ bfrag xpose(f4 m0, f4 m1, int quad, int cc){
  int P0m0 = (int)pk2(m0[0], m0[1]);
  int P1m0 = (int)pk2(m0[2], m0[3]);
  int P0m1 = (int)pk2(m1[0], m1[1]);
  int P1m1 = (int)pk2(m1[2], m1[3]);
  int srcA = ((quad & 1) << 5) + cc;
  int srcB = srcA + 16;
  int hi = quad >> 1;
  int a0 = __shfl(P0m0, srcA, 64), a1 = __shfl(P0m1, srcA, 64);
  int b0 = __shfl(P1m0, srcA, 64), b1 = __shfl(P1m1, srcA, 64);
  int c0 = __shfl(P0m0, srcB, 64), c1 = __shfl(P0m1, srcB, 64);
  int d0 = __shfl(P1m0, srcB, 64), d1 = __shfl(P1m1, srcB, 64);
  union { bfrag f; int u[4]; } r;
  r.u[0] = hi ? a1 : a0;
  r.u[1] = hi ? b1 : b0;
  r.u[2] = hi ? c1 : c0;
  r.u[3] = hi ? d1 : d0;
  return r.f;
}

// 32ch x 32tok sub-GEMM: A = wt rows [ocb,ocb+32), B = x tokens [tb,tb+32) from LDS.
__device__ __forceinline__ void subgemm32(const unsigned short* __restrict__ wt,
                                          const unsigned short* lx,
                                          const float* __restrict__ bqkv,
                                          int ocb, int tb, int quad, int cc,
                                          bfrag& f0, bfrag& f1)
{
  f4 acc[2][2];
  acc[0][0] = (f4){0,0,0,0}; acc[0][1] = (f4){0,0,0,0};
  acc[1][0] = (f4){0,0,0,0}; acc[1][1] = (f4){0,0,0,0};
  #pragma unroll
  for (int ks = 0; ks < 8; ++ks){
    bfrag a0 = *(const bfrag*)(wt + (ocb +      cc)*256 + ks*32 + quad*8);
    bfrag a1 = *(const bfrag*)(wt + (ocb + 16 + cc)*256 + ks*32 + quad*8);
    bfrag b0 = *(const bfrag*)(&lx[swx(tb +      cc, ks*4 + quad)*8]);
    bfrag b1 = *(const bfrag*)(&lx[swx(tb + 16 + cc, ks*4 + quad)*8]);
    acc[0][0] = mfma16(a0, b0, acc[0][0]);
    acc[0][1] = mfma16(a0, b1, acc[0][1]);
    acc[1][0] = mfma16(a1, b0, acc[1][0]);
    acc[1][1] = mfma16(a1, b1, acc[1][1]);
  }
  #pragma unroll
  for (int mt = 0; mt < 2; ++mt)
    #pragma unroll
    for (int r = 0; r < 4; ++r){
      float bb = bqkv[ocb + mt*16 + quad*4 + r];
      acc[mt][0][r] += bb;
      acc[mt][1][r] += bb;
    }
  f0 = xpose(acc[0][0], acc[1][0], quad, cc);
  f1 = xpose(acc[0][1], acc[1][1], quad, cc);
}

// S (QK^T) for one 16-row tile from register frags; biases added in place;
// Z = m + log(sum). SA[jt][r] = logits (i = quad*4+r, j = jt*16+cc).
__device__ __forceinline__ void logits_it(bfrag aq, const bfrag* kf,
    int iibase, int quad, int cc, int h,
    const float* __restrict__ relt, float ego,
    f4 (&SA)[4], float (&Z)[4])
{
  #pragma unroll
  for (int jt = 0; jt < 4; ++jt){
    f4 z = (f4){0,0,0,0};
    SA[jt] = mfma16(aq, kf[jt], z);
  }
  #pragma unroll
  for (int jt = 0; jt < 4; ++jt){
    int jj = jt*16 + cc;
    int yj = jj >> 3, xj = jj & 7;
    #pragma unroll
    for (int r = 0; r < 4; ++r){
      int ii = iibase + r;
      int ridx = ((ii >> 3) - yj + 7)*15 + ((ii & 7) - xj + 7);
      SA[jt][r] += relt[ridx*8 + h] + ego;
    }
  }
  #pragma unroll
  for (int r = 0; r < 4; ++r){
    float m = fmaxf(fmaxf(SA[0][r], SA[1][r]), fmaxf(SA[2][r], SA[3][r]));
    for (int off = 1; off < 16; off <<= 1) m = fmaxf(m, __shfl_xor(m, off, 64));
    float s = 0.0f;
    #pragma unroll
    for (int jt = 0; jt < 4; ++jt) s += __expf(SA[jt][r] - m);
    for (int off = 1; off < 16; off <<= 1) s += __shfl_xor(s, off, 64);
    Z[r] = m + __logf(s);
  }
}

// Blended P (16 rows x 32 j per chunk) -> wave-private LDS tile -> PV MFMA.
__device__ __forceinline__ void pv_it(const f4 (&SA)[4], const float (&Z)[4],
    int quad, int cc, unsigned short* Pt, const unsigned short* vts,
    float ws0, float ws1, f4* yit)
{
  #pragma unroll
  for (int chunk = 0; chunk < 2; ++chunk){
    #pragma unroll
    for (int jtl = 0; jtl < 2; ++jtl){
      int jt = chunk*2 + jtl;
      #pragma unroll
      for (int r = 0; r < 4; ++r){
        float av = SA[jt][r];
        float rl = fmaxf(av, 0.0f);
        float p = ws0 * __expf(av - Z[r]) + ws1 * rl * rl;
        Pt[(quad*4 + r)*32 + jtl*16 + cc] = f2bf(p);
      }
    }
    bfrag pa = *(const bfrag*)(&Pt[cc*32 + quad*8]);
    #pragma unroll
    for (int nt = 0; nt < 2; ++nt){
      int row = nt*16 + cc;
      bfrag pb = *(const bfrag*)(&vts[row*64 + (((chunk*4 + quad) ^ (row & 7)) << 3)]);
      yit[nt] = mfma16(pa, pb, yit[nt]);
    }
  }
}

// ---------------------------------------------------------------------------
// Prep: bf16 W^T (q-scaled) + fused qkv bias.
// ---------------------------------------------------------------------------
__global__ void prep_kernel(const float* __restrict__ Wq,  const float* __restrict__ bq,
                            const float* __restrict__ Wkv, const float* __restrict__ bkv,
                            const float* __restrict__ Wp,
                            unsigned short* __restrict__ wt, float* __restrict__ bqkv)
{
  const int bid = blockIdx.x, tid = threadIdx.x;
  if (bid < 256) {                        // tiled weight transpose + bf16
    __shared__ float t[32][33];
    const int r0 = (bid >> 3) * 32;
    const int c0 = (bid & 7) * 32;
    const int rl = tid & 31, ch = tid >> 5;
    for (int k = 0; k < 4; ++k){
      int c = c0 + ch + k*8, r = r0 + rl;
      float v;
      if (r < 256)      v = Wq[c*256 + r] * SCALE;
      else if (r < 768) v = Wkv[c*512 + (r - 256)];
      else              v = Wp[c*256 + (r - 768)];
      t[rl][ch + k*8] = v;
    }
    __syncthreads();
    for (int k = 0; k < 4; ++k){
      int orr = ch + k*8;
      wt[(r0 + orr)*256 + c0 + rl] = f2bf(t[orr][rl]);
    }
  } else {                                // fused qkv bias (q part scaled)
    for (int j = tid; j < 768; j += 256)
      bqkv[j] = (j < 256) ? bq[j]*SCALE : bkv[j - 256];
  }
}

// ---------------------------------------------------------------------------
// Fused window attention: one block per window, 512 threads (8 waves),
// ONE HEAD PER WAVE. q,k in registers (no sharing, no duplication); v and P
// wave-private LDS (lgkmcnt-ordered, NO barrier). Only 3 block barriers:
//   b0 x staged | b1 x dead (y overwrites) | b2 y staged.
// LDS = 72 KiB -> 2 independent blocks/CU at VGPR<=128 (512,4 launch bounds).
//   ldsX 32K: x bf16 swizzled -> y bf16 swizzled
//   ldsV 32K: per-wave vT (32d x 64tok, unit-swizzled)
//   ldsP  8K: per-wave P tiles (16 x 32)
// ---------------------------------------------------------------------------
__global__ __launch_bounds__(512, 4) void attn_kernel(
    const float* __restrict__ x, const float* __restrict__ wvec,
    const float* __restrict__ bp, float* __restrict__ out,
    const unsigned short* __restrict__ wt, const float* __restrict__ bqkv,
    const float* __restrict__ relt, const float* __restrict__ egot,
    const float* __restrict__ aff)
{
  __shared__ unsigned short ldsX[NT*CDIM];       // 32 KiB
  __shared__ unsigned short ldsV[NHEAD*2048];    // 32 KiB
  __shared__ unsigned short ldsP[NHEAD*512];     //  8 KiB

  const int b = blockIdx.x;
  const int tid = threadIdx.x;
  const int wv = tid >> 6, lane = tid & 63;
  const int quad = lane >> 4, cc = lane & 15;
  const int h = wv;                              // one head per wave

  // ---- stage x window -> bf16 ldsX (swizzled) ----
  const float4* xg = (const float4*)(x + (size_t)b*(NT*CDIM));
  #pragma unroll
  for (int it = 0; it < 8; ++it){
    int i4 = tid + it*512;
    float4 v = xg[i4];
    us4 pk = { f2bf(v.x), f2bf(v.y), f2bf(v.z), f2bf(v.w) };
    int row = i4 >> 6, u = (i4 & 63) >> 1, hf = i4 & 1;
    *(us4*)(&ldsX[swx(row, u)*8 + hf*4]) = pk;
  }
  // blend weights + ego bias (closed-form dmax over the 4 grid corners)
  float w0 = wvec[0], w1 = wvec[1];
  float wm = fmaxf(w0, w1);
  float e0 = __expf(w0 - wm), e1 = __expf(w1 - wm);
  float ws0 = e0/(e0+e1), ws1 = e1/(e0+e1);
  float ego;
  {
    float ex0=(aff[0]+aff[1])*128.f+aff[2],  ey0=(aff[3]+aff[4])*128.f+aff[5];
    float ex1=(aff[6]+aff[7])*128.f+aff[8],  ey1=(aff[9]+aff[10])*128.f+aff[11];
    float dmax = 0.f;
    #pragma unroll
    for (int c = 0; c < 4; ++c){
      float cx = (c & 1) ? 252.f : 4.f, cy = (c >> 1) ? 252.f : 4.f;
      float d0x=cx-ex0, d0y=cy-ey0, d1x=cx-ex1, d1y=cy-ey1;
      dmax = fmaxf(dmax, fmaxf(sqrtf(d0x*d0x+d0y*d0y), sqrtf(d1x*d1x+d1y*d1y)));
    }
    dmax += 1e-6f;
    int cv = b >> 10, wi = b & 1023;
    float cx = (float)((wi & 31)*8 + 4), cy = (float)((wi >> 5)*8 + 4);
    float ex = cv ? ex1 : ex0, ey = cv ? ey1 : ey0;
    float dx = cx - ex, dy = cy - ey;
    float dd = sqrtf(dx*dx + dy*dy);
    float ang = atan2f(dy, dx);
    int db = (int)(dd/dmax*3.0f);
    int ab = (int)((ang + PI_F)/(2.0f*PI_F)*3.0f);
    ego = egot[(db*4 + ab)*8 + h];
  }
  __syncthreads();                               // b0: x staged

  // ---- phase 1 (wave-local): q,k -> register frags; v -> wave-private vT ----
  bfrag aq[4], kf[4];
  subgemm32(wt, ldsX, bqkv, h*32,       0,  quad, cc, aq[0], aq[1]);
  subgemm32(wt, ldsX, bqkv, h*32,       32, quad, cc, aq[2], aq[3]);
  subgemm32(wt, ldsX, bqkv, 256 + h*32, 0,  quad, cc, kf[0], kf[1]);
  subgemm32(wt, ldsX, bqkv, 256 + h*32, 32, quad, cc, kf[2], kf[3]);
  unsigned short* vs = &ldsV[wv*2048];
  {
    const int ocb = 512 + h*32;
    #pragma unroll
    for (int tb = 0; tb < 64; tb += 32){
      f4 vacc[2][2];
      vacc[0][0] = (f4){0,0,0,0}; vacc[0][1] = (f4){0,0,0,0};
      vacc[1][0] = (f4){0,0,0,0}; vacc[1][1] = (f4){0,0,0,0};
      #pragma unroll
      for (int ks = 0; ks < 8; ++ks){
        bfrag a0 = *(const bfrag*)(wt + (ocb +      cc)*256 + ks*32 + quad*8);
        bfrag a1 = *(const bfrag*)(wt + (ocb + 16 + cc)*256 + ks*32 + quad*8);
        bfrag b0 = *(const bfrag*)(&ldsX[swx(tb +      cc, ks*4 + quad)*8]);
        bfrag b1 = *(const bfrag*)(&ldsX[swx(tb + 16 + cc, ks*4 + quad)*8]);
        vacc[0][0] = mfma16(a0, b0, vacc[0][0]);
        vacc[0][1] = mfma16(a0, b1, vacc[0][1]);
        vacc[1][0] = mfma16(a1, b0, vacc[1][0]);
        vacc[1][1] = mfma16(a1, b1, vacc[1][1]);
      }
      #pragma unroll
      for (int mt = 0; mt < 2; ++mt)
        #pragma unroll
        for (int ntl = 0; ntl < 2; ++ntl){
          int tok = tb + ntl*16 + cc;
          int tu = tok >> 3, te = tok & 7;
          #pragma unroll
          for (int r = 0; r < 4; ++r){
            int d = mt*16 + quad*4 + r;
            vs[d*64 + ((tu ^ (d & 7)) << 3) + te] =
                f2bf(vacc[mt][ntl][r] + bqkv[ocb + d]);
          }
        }
    }
  }

  // ---- phase 2 (wave-local, it-sequential): S -> softmax -> P -> PV ----
  f4 yacc[4][2];
  #pragma unroll
  for (int it = 0; it < 4; ++it){
    yacc[it][0] = (f4){0,0,0,0}; yacc[it][1] = (f4){0,0,0,0};
  }
  unsigned short* Pt = &ldsP[wv*512];
  #pragma unroll
  for (int it = 0; it < 4; ++it){
    f4 SA[4]; float Z[4];
    logits_it(aq[it], kf, it*16 + quad*4, quad, cc, h, relt, ego, SA, Z);
    pv_it(SA, Z, quad, cc, Pt, vs, ws0, ws1, yacc[it]);
  }
  __syncthreads();                               // b1: all x reads done

  // ---- y (64x256 bf16, token-major, swizzled) into ldsX ----
  #pragma unroll
  for (int it = 0; it < 4; ++it)
    #pragma unroll
    for (int nt = 0; nt < 2; ++nt)
      #pragma unroll
      for (int r = 0; r < 4; ++r){
        int ii = it*16 + quad*4 + r;
        int col = h*32 + nt*16 + cc;
        ldsX[swx(ii, col>>3)*8 + (col&7)] = f2bf(yacc[it][nt][r]);
      }
  __syncthreads();                               // b2: y staged

  // ---- phase 3: out = y @ Wp + bp (wave -> 16 tok x 128 oc) ----
  {
    const int mt = wv & 3;
    const int cb = (wv >> 2)*128;
    f4 o[8];
    #pragma unroll
    for (int nt = 0; nt < 8; ++nt) o[nt] = (f4){0,0,0,0};
    #pragma unroll
    for (int ks = 0; ks < 8; ++ks){
      bfrag ay = *(const bfrag*)(&ldsX[swx(mt*16 + cc, ks*4 + quad)*8]);
      #pragma unroll
      for (int nt = 0; nt < 8; ++nt){
        bfrag bw = *(const bfrag*)(wt + (768 + cb + nt*16 + cc)*256 + ks*32 + quad*8);
        o[nt] = mfma16(ay, bw, o[nt]);
      }
    }
    float* og = out + (size_t)b*(NT*CDIM);
    #pragma unroll
    for (int nt = 0; nt < 8; ++nt){
      int col = cb + nt*16 + cc;
      float bpv = bp[col];
      #pragma unroll
      for (int r = 0; r < 4; ++r){
        int tok = mt*16 + quad*4 + r;
        og[tok*256 + col] = o[nt][r] + bpv;
      }
    }
  }
}

extern "C" void kernel_launch(void* const* d_in, const int* in_sizes, int n_in,
                              void* d_out, int out_size, void* d_ws, size_t ws_size,
                              hipStream_t stream)
{
  const float* x    = (const float*)d_in[0];
  const float* aff  = (const float*)d_in[1];
  const float* Wq   = (const float*)d_in[2];
  const float* bq   = (const float*)d_in[3];
  const float* Wkv  = (const float*)d_in[4];
  const float* bkv  = (const float*)d_in[5];
  const float* Wp   = (const float*)d_in[6];
  const float* bp   = (const float*)d_in[7];
  const float* relt = (const float*)d_in[8];
  const float* egot = (const float*)d_in[9];
  const float* w    = (const float*)d_in[10];
  float* out = (float*)d_out;

  char* ws = (char*)d_ws;
  unsigned short* wt = (unsigned short*)ws;       // 512 KiB bf16 W^T
  float* bqkv = (float*)(ws + 524288);            //   3 KiB

  hipLaunchKernelGGL(prep_kernel, dim3(257), dim3(256), 0, stream,
                     Wq, bq, Wkv, bkv, Wp, wt, bqkv);
  hipLaunchKernelGGL(attn_kernel, dim3(2048), dim3(512), 0, stream,
                     x, w, bp, out, wt, bqkv, relt, egot, aff);
}